// Round 7
// baseline (144.130 us; speedup 1.0000x reference)
//
#include <hip/hip_runtime.h>

#define H 512
#define W 512
#define HW (H * W)
#define BATCH 32
#define KS 5
#define B_CHUNK 2                      // batches per block; 16 chunks
#define RING 8                         // LDS row ring slots (window 6 + 2 in flight)
#define LROW 520                       // [4 zero][512 data][4 zero]
#define LTILE (RING * LROW)            // 4160 floats per batch
#define LDS_FLOATS (B_CHUNK * LTILE)   // 8320 floats = 33,280 B -> 4 blocks/CU
#define STEPS 4                        // row-pairs per block (8 output rows)

typedef const __attribute__((address_space(1))) void gv_t;
typedef __attribute__((address_space(3))) void lv_t;
typedef float nf4 __attribute__((ext_vector_type(4)));

__device__ __forceinline__ void async_cp16(const float* src, float* lds_dst) {
    __builtin_amdgcn_global_load_lds((gv_t*)src, (lv_t*)lds_dst, 16, 0, 0);
}

// Stage one (batch,row,half) 1 KB unit into its ring slot. gr and half are
// wave-uniform. OOB rows are zero-filled (ds_write) instead.
__device__ __forceinline__ void stage_unit(const float* __restrict__ fb,
                                           float* ldsb, int gr, int half,
                                           int lane) {
    float* dst = ldsb + (gr & 7) * LROW + 4 + half * 256;
    if (gr >= 0 && gr < H) {
        async_cp16(fb + (size_t)gr * W + half * 256 + lane * 4, dst);
    } else {
        *reinterpret_cast<nf4*>(dst + lane * 4) = (nf4)0.f;
    }
}

// Rolling-rows pipeline: block = 2 output rows x 512 cols x 2 batches per
// step, 4 steps walking down rows with an 8-slot LDS row ring. Per step only
// the 2 NEW f rows are staged (4 KB) -> small barrier drains, f staged once
// (no 3x halo re-read). One barrier per step. K tap rows double-buffered in
// regs across the whole walk (global tap counter parity).
__global__ __launch_bounds__(256, 4) void op2d_kernel(
    const float* __restrict__ f,   // (B,H,W)
    const float* __restrict__ K,   // (5,5,H,W)
    const float* __restrict__ dt,  // (B,)
    float* __restrict__ out)       // (B,H,W)
{
    __shared__ float lds[LDS_FLOATS];

    const int tid   = threadIdx.x;
    const int lane  = tid & 63;
    const int wave  = tid >> 6;
    const int w0    = (tid & 127) * 4;          // 0..508
    const int lr    = tid >> 7;                 // 0 or 1
    const int hblk  = blockIdx.x * (2 * STEPS); // first output row of block
    const int chunk = blockIdx.y;               // 0..15
    const int bg0   = chunk * B_CHUNK;

    // Zero all of LDS (pads + safety); must complete before staging writes.
    for (int idx = tid * 4; idx < LDS_FLOATS; idx += 1024)
        *reinterpret_cast<nf4*>(lds + idx) = (nf4)0.f;
    __syncthreads();

    const float* fb0 = f + (size_t)bg0 * HW;
    const float* fb1 = fb0 + HW;

    // ---- prologue: stage rows hblk-2 .. hblk+3, both batches (24 units) ----
#pragma unroll
    for (int k = 0; k < 6; ++k) {
        const int u    = wave * 6 + k;     // 0..23
        const int bu   = u / 12;
        const int rem  = u % 12;
        const int r    = rem >> 1;
        const int half = rem & 1;
        stage_unit(bu ? fb1 : fb0, lds + bu * LTILE, hblk - 2 + r, half, lane);
    }

    // K tap-row 0 of step 0: in flight across the staging drain.
    float4 Kv[2][KS];
    {
        const float* Kb = K + (size_t)(hblk + lr) * W + w0;
#pragma unroll
        for (int j = 0; j < KS; ++j)
            Kv[0][j] = *reinterpret_cast<const float4*>(Kb + (size_t)j * HW);
    }

    const float dtb[B_CHUNK] = { dt[bg0], dt[bg0 + 1] };

    __syncthreads();   // drains vmcnt(0): prologue tiles + Kv[0] resident

#pragma unroll
    for (int s = 0; s < STEPS; ++s) {
        const int hs = hblk + 2 * s;       // this step's first output row
        const int h  = hs + lr;            // this thread's output row

        // Prefetch the 2 new f rows for step s+1 (slots not in current window).
        if (s + 1 < STEPS) {
#pragma unroll
            for (int k = 0; k < 2; ++k) {
                const int u    = wave * 2 + k;  // 0..7
                const int bu   = u >> 2;
                const int r    = (u >> 1) & 1;
                const int half = u & 1;
                stage_unit(bu ? fb1 : fb0, lds + bu * LTILE, hs + 4 + r, half, lane);
            }
        }

        const float* Kstep = K + (size_t)h * W + w0;
        float acc[B_CHUNK][4] = {{0.f, 0.f, 0.f, 0.f}, {0.f, 0.f, 0.f, 0.f}};
        float fc[B_CHUNK][4];

#pragma unroll
        for (int i = 0; i < KS; ++i) {
            const int g = s * KS + i;      // global tap-row counter (parity)
            // Prefetch next tap row (same step, or row 0 of next step).
            if (i + 1 < KS) {
#pragma unroll
                for (int j = 0; j < KS; ++j)
                    Kv[(g + 1) & 1][j] = *reinterpret_cast<const float4*>(
                        Kstep + (size_t)((i + 1) * KS + j) * HW);
            } else if (s + 1 < STEPS) {
                const float* Knext = Kstep + 2 * W;   // next step's row (h+2)
#pragma unroll
                for (int j = 0; j < KS; ++j)
                    Kv[(g + 1) & 1][j] = *reinterpret_cast<const float4*>(
                        Knext + (size_t)j * HW);
            }
            const float4* Kc = Kv[g & 1];

#pragma unroll
            for (int b = 0; b < B_CHUNK; ++b) {
                const int slot = (h + i - 2) & 7;
                const float* row = lds + b * LTILE + slot * LROW + w0;
                const float4 ra = *reinterpret_cast<const float4*>(row);      // w0-4..w0-1
                const float4 rb = *reinterpret_cast<const float4*>(row + 4);  // w0  ..w0+3
                const float4 rc = *reinterpret_cast<const float4*>(row + 8);  // w0+4..w0+7
                const float buf[12] = { ra.x, ra.y, ra.z, ra.w,
                                        rb.x, rb.y, rb.z, rb.w,
                                        rc.x, rc.y, rc.z, rc.w };
                if (i == 2) { fc[b][0] = rb.x; fc[b][1] = rb.y;
                              fc[b][2] = rb.z; fc[b][3] = rb.w; }
#pragma unroll
                for (int j = 0; j < KS; ++j) {
                    acc[b][0] += Kc[j].x * buf[j + 2];
                    acc[b][1] += Kc[j].y * buf[j + 3];
                    acc[b][2] += Kc[j].z * buf[j + 4];
                    acc[b][3] += Kc[j].w * buf[j + 5];
                }
            }
        }

#pragma unroll
        for (int b = 0; b < B_CHUNK; ++b) {
            nf4 o;
            o.x = fmaxf(fc[b][0] + acc[b][0] * dtb[b], 0.f);
            o.y = fmaxf(fc[b][1] + acc[b][1] * dtb[b], 0.f);
            o.z = fmaxf(fc[b][2] + acc[b][2] * dtb[b], 0.f);
            o.w = fmaxf(fc[b][3] + acc[b][3] * dtb[b], 0.f);
            __builtin_nontemporal_store(o,
                reinterpret_cast<nf4*>(out + ((size_t)(bg0 + b) * H + h) * W + w0));
        }

        // One barrier per step: drains next step's f prefetch (and Kv), and
        // protects ring slots (prefetch of s+2 overwrites rows last used in s).
        __syncthreads();
    }
}

extern "C" void kernel_launch(void* const* d_in, const int* in_sizes, int n_in,
                              void* d_out, int out_size, void* d_ws, size_t ws_size,
                              hipStream_t stream) {
    const float* f  = (const float*)d_in[0];   // (32,512,512)
    const float* K  = (const float*)d_in[1];   // (5,5,512,512)
    const float* dt = (const float*)d_in[2];   // (32,)
    float* out = (float*)d_out;

    dim3 block(256);
    // x = row-group (64), y = chunk (16): all 1024 blocks co-resident (4/CU);
    // same-K blocks are 64 IDs apart = 0 mod 8 -> same XCD.
    dim3 grid(H / (2 * STEPS), BATCH / B_CHUNK);
    op2d_kernel<<<grid, block, 0, stream>>>(f, K, dt, out);
}

// Round 8
// 120.454 us; speedup vs baseline: 1.1966x; 1.1966x over previous
//
#include <hip/hip_runtime.h>

#define H 512
#define W 512
#define HW (H * W)
#define BATCH 32
#define KS 5
#define NROWS 8     // rows walked per block
#define NB 2        // batches per thread (K reused in-register across both)

typedef float nf4 __attribute__((ext_vector_type(4)));

// Load one 12-float padded window row (cols w0-4..w0+7) as 3 float4s.
// OOB rows/cols produce zeros. gr is block-uniform (branch, not divergence).
__device__ __forceinline__ void load_row(const float* __restrict__ fb, int gr,
                                         bool wl, bool wr, int w0, nf4* d) {
    if (gr >= 0 && gr < H) {
        const float* row = fb + (size_t)gr * W;
        d[0] = wl ? *reinterpret_cast<const nf4*>(row + w0 - 4) : (nf4)0.f;
        d[1] =      *reinterpret_cast<const nf4*>(row + w0);
        d[2] = wr ? *reinterpret_cast<const nf4*>(row + w0 + 4) : (nf4)0.f;
    } else {
        d[0] = (nf4)0.f; d[1] = (nf4)0.f; d[2] = (nf4)0.f;
    }
}

// NO LDS, NO BARRIERS. 128 threads/block; thread = 4 cols x 2 batches,
// walking 8 rows with a register-resident 5-row x 12-col f window per batch
// (slot = (row - hblk + 2) mod 5; all indices compile-time under full unroll).
// Per step: prefetch next f row (used a full step later) + K tap-rows
// double-buffered one i-iteration ahead. Prefetches stay in flight across
// steps because nothing ever drains vmcnt collectively.
__global__ __launch_bounds__(128, 2) void op2d_kernel(
    const float* __restrict__ f,   // (B,H,W)
    const float* __restrict__ K,   // (5,5,H,W)
    const float* __restrict__ dt,  // (B,)
    float* __restrict__ out)       // (B,H,W)
{
    const int tid  = threadIdx.x;            // 0..127
    const int w0   = tid * 4;                // 0..508
    const int hblk = blockIdx.x * NROWS;     // first output row
    const int b0   = blockIdx.y * NB;        // first batch

    const bool wl = (w0 >= 4);
    const bool wr = (w0 <= 504);

    const float* fb[NB] = { f + (size_t)b0 * HW, f + (size_t)(b0 + 1) * HW };
    const float dtb[NB] = { dt[b0], dt[b0 + 1] };

    // f window: win[b][slot][0..2], slot = (global_row - hblk + 2) mod 5.
    nf4 win[NB][5][3];

    // ---- prologue: rows hblk-2 .. hblk+2 -> slots 0..4 ----
#pragma unroll
    for (int rr = 0; rr < 5; ++rr) {
#pragma unroll
        for (int b = 0; b < NB; ++b)
            load_row(fb[b], hblk - 2 + rr, wl, wr, w0, win[b][rr]);
    }

    // K tap-row 0 of step 0 (in flight alongside the prologue f loads).
    nf4 Kv[2][KS];
#pragma unroll
    for (int j = 0; j < KS; ++j)
        Kv[0][j] = *reinterpret_cast<const nf4*>(
            K + ((size_t)j * H + hblk) * W + w0);

#pragma unroll
    for (int s = 0; s < NROWS; ++s) {
        const int r = hblk + s;              // output row this step

        // Prefetch f row r+3 (enters window slot s%5 at step end; first
        // consumed at step s+1, tap i=4 -> ~a full step of latency cover).
        nf4 nxt[NB][3];
#pragma unroll
        for (int b = 0; b < NB; ++b)
            load_row(fb[b], r + 3, wl, wr, w0, nxt[b]);

        float acc[NB][4] = {{0.f,0.f,0.f,0.f},{0.f,0.f,0.f,0.f}};
        float fc[NB][4];

#pragma unroll
        for (int i = 0; i < KS; ++i) {
            const int g = s * KS + i;        // global tap counter (parity)
            // Prefetch next K tap-row (same step, or row 0 of next step).
            if (i + 1 < KS) {
#pragma unroll
                for (int j = 0; j < KS; ++j)
                    Kv[(g + 1) & 1][j] = *reinterpret_cast<const nf4*>(
                        K + ((size_t)((i + 1) * KS + j) * H + r) * W + w0);
            } else if (s + 1 < NROWS) {
#pragma unroll
                for (int j = 0; j < KS; ++j)
                    Kv[(g + 1) & 1][j] = *reinterpret_cast<const nf4*>(
                        K + ((size_t)j * H + (r + 1)) * W + w0);
            }
            const nf4* Kc = Kv[g & 1];

#pragma unroll
            for (int b = 0; b < NB; ++b) {
                const int slot = (s + i) % 5;          // row r+i-2
                const nf4 ra = win[b][slot][0];
                const nf4 rb = win[b][slot][1];
                const nf4 rc = win[b][slot][2];
                const float buf[12] = { ra.x, ra.y, ra.z, ra.w,
                                        rb.x, rb.y, rb.z, rb.w,
                                        rc.x, rc.y, rc.z, rc.w };
                if (i == 2) { fc[b][0] = rb.x; fc[b][1] = rb.y;
                              fc[b][2] = rb.z; fc[b][3] = rb.w; }
#pragma unroll
                for (int j = 0; j < KS; ++j) {
                    acc[b][0] += Kc[j].x * buf[j + 2];
                    acc[b][1] += Kc[j].y * buf[j + 3];
                    acc[b][2] += Kc[j].z * buf[j + 4];
                    acc[b][3] += Kc[j].w * buf[j + 5];
                }
            }
        }

        // Store both batches' outputs for row r (2 KB contiguous per wave-pair).
#pragma unroll
        for (int b = 0; b < NB; ++b) {
            nf4 o;
            o.x = fmaxf(fc[b][0] + acc[b][0] * dtb[b], 0.f);
            o.y = fmaxf(fc[b][1] + acc[b][1] * dtb[b], 0.f);
            o.z = fmaxf(fc[b][2] + acc[b][2] * dtb[b], 0.f);
            o.w = fmaxf(fc[b][3] + acc[b][3] * dtb[b], 0.f);
            __builtin_nontemporal_store(o,
                reinterpret_cast<nf4*>(out + ((size_t)(b0 + b) * H + r) * W + w0));
        }

        // Rotate: new bottom row (r+3) replaces departing row (r-2), slot s%5.
#pragma unroll
        for (int b = 0; b < NB; ++b) {
            win[b][s % 5][0] = nxt[b][0];
            win[b][s % 5][1] = nxt[b][1];
            win[b][s % 5][2] = nxt[b][2];
        }
    }
}

extern "C" void kernel_launch(void* const* d_in, const int* in_sizes, int n_in,
                              void* d_out, int out_size, void* d_ws, size_t ws_size,
                              hipStream_t stream) {
    const float* f  = (const float*)d_in[0];   // (32,512,512)
    const float* K  = (const float*)d_in[1];   // (5,5,512,512)
    const float* dt = (const float*)d_in[2];   // (32,)
    float* out = (float*)d_out;

    dim3 block(128);
    // x = row-group (64), y = batch-pair (16): 1024 blocks, 4/CU, all
    // co-resident; same-K blocks are 64 IDs apart = 0 mod 8 -> same XCD.
    dim3 grid(H / NROWS, BATCH / NB);
    op2d_kernel<<<grid, block, 0, stream>>>(f, K, dt, out);
}